// Round 3
// baseline (566.461 us; speedup 1.0000x reference)
//
#include <hip/hip_runtime.h>

// Problem constants (match reference setup_inputs)
constexpr int   B_   = 8;
constexpr int   RES  = 160;
constexpr long long GCELLS = (long long)B_ * RES * RES * RES;   // 32,768,000
constexpr float EMA  = 0.95f;
constexpr float THRE = 0.01f;
constexpr unsigned int MAGIC = 0x0CCB1E55u;

// ext_vector types so __builtin_nontemporal_{load,store} accept them
typedef float        f32x4 __attribute__((ext_vector_type(4)));
typedef int          i32x4 __attribute__((ext_vector_type(4)));
typedef unsigned int u32x4 __attribute__((ext_vector_type(4)));

// ---------------------------------------------------------------------------
// WS path, pass 0: first-launch-only init of the persistent scratch in d_ws.
// Steady state: every block reads the flag (set by the scatter of launch 1)
// and exits immediately (~3 us for 8K blocks). Idempotent under replay.
// Self-healing: if the harness ever clobbers d_ws, flag != MAGIC -> re-zero.
__global__ void __launch_bounds__(256)
occ_guard_init_kernel(u32x4* __restrict__ scratch,
                      const unsigned int* __restrict__ flag,
                      long long nquads) {
    if (*flag == MAGIC) return;
    long long stride = (long long)gridDim.x * blockDim.x;
    for (long long i = (long long)blockIdx.x * blockDim.x + threadIdx.x;
         i < nquads; i += stride) {
        u32x4 z = {0u, 0u, 0u, 0u};
        scratch[i] = z;
    }
}

// Fallback path, pass 0: zero the out_occ-resident scratch every iteration
// (required there because the harness may re-poison d_out between launches).
__global__ void __launch_bounds__(256)
occ_zero_kernel(u32x4* __restrict__ scratch, long long nquads) {
    long long i = (long long)blockIdx.x * blockDim.x + threadIdx.x;
    if (i >= nquads) return;
    u32x4 z = {0u, 0u, 0u, 0u};
    scratch[i] = z;
}

// Pass 1: per-point scatter, 4 points per thread.
// scratch[lin] = atomicMax over (float_bits(val)+1). val >= 0 so uint compare of
// float bits is monotone; +1 makes 0 a clean "untouched" sentinel (reversible s-1).
// NOTE (r0/r1/r2 evidence): dur invariant to per-thread structure and cache
// policy; WRITE_SIZE == one 64B-line writeback per touched line. Bound by the
// memory-side atomic path (~25 G atomics/s). Do not churn further.
__global__ void __launch_bounds__(256)
occ_scatter_kernel(const f32x4* __restrict__ pts4,
                   const i32x4* __restrict__ bidx4,
                   const f32x4* __restrict__ val4,
                   const float* __restrict__ pts,
                   const int*   __restrict__ bidx,
                   const float* __restrict__ val,
                   unsigned int* __restrict__ scratch,
                   unsigned int* flag,          // ws mode: set MAGIC (nullptr in fb)
                   int nq, int rem) {
    int i = blockIdx.x * blockDim.x + threadIdx.x;
    if (flag && i == 0) *flag = MAGIC;   // marks ws scratch initialized (idempotent)
    if (i < nq) {
        // 4 points = 3 consecutive float4 loads (48 B), fully vectorized
        f32x4 p0 = pts4[3 * i + 0];
        f32x4 p1 = pts4[3 * i + 1];
        f32x4 p2 = pts4[3 * i + 2];
        i32x4 b  = bidx4[i];
        f32x4 v  = val4[i];

        float px[4] = {p0.x, p0.w, p1.z, p2.y};
        float py[4] = {p0.y, p1.x, p1.w, p2.z};
        float pz[4] = {p0.z, p1.y, p2.x, p2.w};
        int   bb[4] = {b.x, b.y, b.z, b.w};
        float vv[4] = {v.x, v.y, v.z, v.w};

#pragma unroll
        for (int k = 0; k < 4; ++k) {
            // Match jnp: ((p / 2 + 0.5) * res).astype(int32), clamped to [0, res-1].
            int gx = (int)((px[k] / 2.0f + 0.5f) * (float)RES);
            int gy = (int)((py[k] / 2.0f + 0.5f) * (float)RES);
            int gz = (int)((pz[k] / 2.0f + 0.5f) * (float)RES);
            gx = min(max(gx, 0), RES - 1);
            gy = min(max(gy, 0), RES - 1);
            gz = min(max(gz, 0), RES - 1);
            int lin = ((bb[k] * RES + gx) * RES + gy) * RES + gz;   // < 2^31
            atomicMax(&scratch[lin], __float_as_uint(vv[k]) + 1u);
        }
    } else if (i == nq && rem > 0) {
        // scalar tail (N % 4 points), normally rem == 0
        for (int k = 0; k < rem; ++k) {
            int j = nq * 4 + k;
            float x = pts[3 * j + 0];
            float y = pts[3 * j + 1];
            float z = pts[3 * j + 2];
            int gx = (int)((x / 2.0f + 0.5f) * (float)RES);
            int gy = (int)((y / 2.0f + 0.5f) * (float)RES);
            int gz = (int)((z / 2.0f + 0.5f) * (float)RES);
            gx = min(max(gx, 0), RES - 1);
            gy = min(max(gy, 0), RES - 1);
            gz = min(max(gz, 0), RES - 1);
            int lin = ((bidx[j] * RES + gx) * RES + gy) * RES + gz;
            atomicMax(&scratch[lin], __float_as_uint(val[j]) + 1u);
        }
    }
}

// Pass 2: per-cell finalize.
// WSMODE: grid streamed NT (keeps MALL hot-set = scratch 131MB + pts/bidx/val
// 82MB < 256MB); scratch reset to 0 inline (regular store -> zeros stay
// MALL-resident for next iteration's atomics) -- this REPLACES the standalone
// zero pass. Fallback: round-2 behavior (scratch aliases out_occ, no reset).
// Outputs always NT (never re-read; don't thrash the MALL).
template <bool WSMODE>
__global__ void __launch_bounds__(256)
occ_finalize_kernel(const f32x4* __restrict__ grid,
                    f32x4* __restrict__ out_val,
                    f32x4* __restrict__ out_occ,
                    u32x4* __restrict__ scratch,   // fb: aliases out_occ
                    long long nquads) {
    long long i = (long long)blockIdx.x * blockDim.x + threadIdx.x;
    if (i >= nquads) return;

    f32x4 g = WSMODE ? __builtin_nontemporal_load(&grid[i]) : grid[i];
    u32x4 s = scratch[i];

    f32x4 r;
    r.x = s.x ? fmaxf(g.x * EMA, __uint_as_float(s.x - 1u)) : g.x;
    r.y = s.y ? fmaxf(g.y * EMA, __uint_as_float(s.y - 1u)) : g.y;
    r.z = s.z ? fmaxf(g.z * EMA, __uint_as_float(s.z - 1u)) : g.z;
    r.w = s.w ? fmaxf(g.w * EMA, __uint_as_float(s.w - 1u)) : g.w;

    f32x4 o;
    o.x = (r.x > THRE) ? 1.0f : 0.0f;
    o.y = (r.y > THRE) ? 1.0f : 0.0f;
    o.z = (r.z > THRE) ? 1.0f : 0.0f;
    o.w = (r.w > THRE) ? 1.0f : 0.0f;

    if (WSMODE) {
        u32x4 z = {0u, 0u, 0u, 0u};
        scratch[i] = z;                 // reset for next iteration (fused zero)
    }

    __builtin_nontemporal_store(r, &out_val[i]);
    __builtin_nontemporal_store(o, &out_occ[i]);
}

extern "C" void kernel_launch(void* const* d_in, const int* in_sizes, int n_in,
                              void* d_out, int out_size, void* d_ws, size_t ws_size,
                              hipStream_t stream) {
    const float* grid = (const float*)d_in[0];   // (B,R,R,R) fp32
    const float* pts  = (const float*)d_in[1];   // (N,3) fp32
    const int*   bidx = (const int*)d_in[2];     // (N,) int32
    const float* val  = (const float*)d_in[3];   // (N,) fp32

    float* out_val = (float*)d_out;              // first G floats: new grid
    float* out_occ = out_val + GCELLS;           // second G floats: occ mask

    int n   = in_sizes[1] / 3;                   // N points
    int nq  = n / 4;
    int rem = n % 4;

    long long quads = GCELLS / 4;                // 8,192,000 (divisible by 256)
    int cell_blocks = (int)((quads + 255) / 256);

    bool wsmode = ws_size >= (size_t)GCELLS * 4 + 64;
    unsigned int* scratch = wsmode ? (unsigned int*)d_ws
                                   : (unsigned int*)out_occ;
    unsigned int* flag = wsmode
        ? (unsigned int*)((char*)d_ws + (size_t)GCELLS * 4)
        : nullptr;

    // Pass 0
    if (wsmode) {
        occ_guard_init_kernel<<<8192, 256, 0, stream>>>(
            (u32x4*)scratch, flag, quads);
    } else {
        occ_zero_kernel<<<cell_blocks, 256, 0, stream>>>(
            (u32x4*)scratch, quads);
    }

    // Pass 1: scatter (4 pts/thread + scalar tail thread)
    int sb = (nq + 1 + 255) / 256;
    occ_scatter_kernel<<<sb, 256, 0, stream>>>(
        (const f32x4*)pts, (const i32x4*)bidx, (const f32x4*)val,
        pts, bidx, val, scratch, flag, nq, rem);

    // Pass 2: finalize
    if (wsmode) {
        occ_finalize_kernel<true><<<cell_blocks, 256, 0, stream>>>(
            (const f32x4*)grid, (f32x4*)out_val, (f32x4*)out_occ,
            (u32x4*)scratch, quads);
    } else {
        occ_finalize_kernel<false><<<cell_blocks, 256, 0, stream>>>(
            (const f32x4*)grid, (f32x4*)out_val, (f32x4*)out_occ,
            (u32x4*)scratch, quads);
    }
}

// Round 4
// 535.306 us; speedup vs baseline: 1.0582x; 1.0582x over previous
//
#include <hip/hip_runtime.h>

// Problem constants (match reference setup_inputs)
constexpr int   B_   = 8;
constexpr int   RES  = 160;
constexpr long long GCELLS = (long long)B_ * RES * RES * RES;   // 32,768,000
constexpr float EMA  = 0.95f;
constexpr float THRE = 0.01f;

// Binned-scatter geometry: bucket = lin >> 14 (16384 cells = 64 KB grid slice)
constexpr int BSHIFT = 14;
constexpr int BCELLS = 1 << BSHIFT;            // 16384
constexpr int NB     = (int)(GCELLS >> BSHIFT); // 2000 (exact: 2000*16384 = GCELLS)
constexpr int CAP    = 4096;                   // slots/bucket (mean 2097, sigma ~46)
constexpr int OVCAP  = 65536;                  // emergency spill list

// ext_vector types so __builtin_nontemporal_{load,store} accept them
typedef float        f32x4 __attribute__((ext_vector_type(4)));
typedef unsigned int u32x4 __attribute__((ext_vector_type(4)));

__device__ __forceinline__ int cell_lin(float px, float py, float pz, int b) {
    // Match jnp: ((p / 2 + 0.5) * res).astype(int32), clamped to [0, res-1].
    int gx = (int)((px / 2.0f + 0.5f) * (float)RES);
    int gy = (int)((py / 2.0f + 0.5f) * (float)RES);
    int gz = (int)((pz / 2.0f + 0.5f) * (float)RES);
    gx = min(max(gx, 0), RES - 1);
    gy = min(max(gy, 0), RES - 1);
    gz = min(max(gz, 0), RES - 1);
    return ((b * RES + gx) * RES + gy) * RES + gz;   // < 2^31
}

// ---------------------------------------------------------------------------
// WS path, pass 0: zero the 2000 bucket cursors + overflow cursor (~8 KB).
__global__ void __launch_bounds__(256)
occ_cursor_zero_kernel(unsigned int* __restrict__ gcursor,
                       unsigned int* __restrict__ ovcur) {
    int i = threadIdx.x;
    for (; i < NB; i += 256) gcursor[i] = 0u;
    if (threadIdx.x == 0) *ovcur = 0u;
}

// WS path, pass 1: bin points into per-bucket pair arrays.
// Block-level: LDS histogram -> one global cursor reservation per
// (block,bucket) -> dense appends. Active write frontier ~2000 lines
// (128 KB, LLC-resident) so pair writes become full-line clustered traffic.
__global__ void __launch_bounds__(256)
occ_bin_kernel(const float* __restrict__ pts,
               const int*   __restrict__ bidx,
               const float* __restrict__ val,
               uint2*        __restrict__ binned,
               unsigned int* __restrict__ gcursor,
               unsigned int* __restrict__ ovcur,
               uint2*        __restrict__ ovbuf,
               int n) {
    __shared__ unsigned int hist[NB];   // counts, then per-block running cursor
    __shared__ unsigned int base[NB];   // global base reserved for this block

    int tid = threadIdx.x;
    for (int i = tid; i < NB; i += 256) hist[i] = 0u;
    __syncthreads();

    int per_block = (n + gridDim.x - 1) / gridDim.x;
    int start = blockIdx.x * per_block;
    int end   = min(start + per_block, n);

    // Phase 1: count this block's points per bucket.
    for (int i = start + tid; i < end; i += 256) {
        int lin = cell_lin(pts[3 * i], pts[3 * i + 1], pts[3 * i + 2], bidx[i]);
        atomicAdd(&hist[(unsigned)lin >> BSHIFT], 1u);
    }
    __syncthreads();

    // Phase 2: reserve contiguous ranges in each bucket's array.
    for (int i = tid; i < NB; i += 256) {
        unsigned int c = hist[i];
        base[i] = c ? atomicAdd(&gcursor[i], c) : 0u;
        hist[i] = 0u;                    // reuse as running cursor
    }
    __syncthreads();

    // Phase 3: re-read (LLC-hot) and place pairs.
    for (int i = start + tid; i < end; i += 256) {
        int lin = cell_lin(pts[3 * i], pts[3 * i + 1], pts[3 * i + 2], bidx[i]);
        unsigned int enc = __float_as_uint(val[i]) + 1u;   // val>=0: monotone bits
        unsigned int bk  = (unsigned)lin >> BSHIFT;
        unsigned int r   = atomicAdd(&hist[bk], 1u);
        unsigned int slot = base[bk] + r;
        uint2 p; p.x = (unsigned)lin; p.y = enc;
        if (slot < (unsigned)CAP) {
            binned[(size_t)bk * CAP + slot] = p;
        } else {                         // statistically never (43 sigma)
            unsigned int o = atomicAdd(ovcur, 1u);
            if (o < (unsigned)OVCAP) ovbuf[o] = p;
        }
    }
}

// WS path, pass 2: fused replay + finalize. One block per bucket.
// Buckets are disjoint 64 KB grid slices -> replay uses LDS atomicMax only
// (no device atomics, no global scratch, no zero pass). Then stream the
// slice: grid NT-load -> EMA-max + threshold -> NT-stores.
__global__ void __launch_bounds__(256)
occ_replay_finalize_kernel(const uint2* __restrict__ binned,
                           const unsigned int* __restrict__ gcursor,
                           const unsigned int* __restrict__ ovcur,
                           const uint2* __restrict__ ovbuf,
                           const f32x4* __restrict__ grid,
                           f32x4* __restrict__ out_val,
                           f32x4* __restrict__ out_occ) {
    __shared__ unsigned int win[BCELLS];          // 64 KB window
    int b   = blockIdx.x;
    int tid = threadIdx.x;

    u32x4* w4 = (u32x4*)win;
    u32x4 z = {0u, 0u, 0u, 0u};
    for (int i = tid; i < BCELLS / 4; i += 256) w4[i] = z;
    __syncthreads();

    unsigned int cnt = gcursor[b];
    if (cnt > (unsigned)CAP) cnt = CAP;           // excess went to spill list
    const uint2* bp = binned + (size_t)b * CAP;
    for (unsigned int i = tid; i < cnt; i += 256) {
        uint2 p = bp[i];
        atomicMax(&win[p.x & (BCELLS - 1)], p.y);
    }
    unsigned int oc = *ovcur;                     // normally 0
    if (oc) {
        if (oc > (unsigned)OVCAP) oc = OVCAP;
        for (unsigned int i = tid; i < oc; i += 256) {
            uint2 p = ovbuf[i];
            if ((p.x >> BSHIFT) == (unsigned)b)
                atomicMax(&win[p.x & (BCELLS - 1)], p.y);
        }
    }
    __syncthreads();

    size_t qbase = (size_t)b * (BCELLS / 4);
    for (int c = tid; c < BCELLS / 4; c += 256) {
        f32x4 g = __builtin_nontemporal_load(&grid[qbase + c]);
        u32x4 s = w4[c];

        f32x4 r;
        r.x = s.x ? fmaxf(g.x * EMA, __uint_as_float(s.x - 1u)) : g.x;
        r.y = s.y ? fmaxf(g.y * EMA, __uint_as_float(s.y - 1u)) : g.y;
        r.z = s.z ? fmaxf(g.z * EMA, __uint_as_float(s.z - 1u)) : g.z;
        r.w = s.w ? fmaxf(g.w * EMA, __uint_as_float(s.w - 1u)) : g.w;

        f32x4 o;
        o.x = (r.x > THRE) ? 1.0f : 0.0f;
        o.y = (r.y > THRE) ? 1.0f : 0.0f;
        o.z = (r.z > THRE) ? 1.0f : 0.0f;
        o.w = (r.w > THRE) ? 1.0f : 0.0f;

        __builtin_nontemporal_store(r, &out_val[qbase + c]);
        __builtin_nontemporal_store(o, &out_occ[qbase + c]);
    }
}

// ---------------------------------------------------------------------------
// Fallback path (ws too small) == round-1 best (547 us): zero + scatter +
// finalize with scratch aliasing out_occ.
__global__ void __launch_bounds__(256)
occ_zero_kernel(u32x4* __restrict__ scratch, long long nquads) {
    long long i = (long long)blockIdx.x * blockDim.x + threadIdx.x;
    if (i >= nquads) return;
    u32x4 z = {0u, 0u, 0u, 0u};
    scratch[i] = z;
}

__global__ void __launch_bounds__(256)
occ_scatter_kernel(const float* __restrict__ pts,
                   const int*   __restrict__ bidx,
                   const float* __restrict__ val,
                   unsigned int* __restrict__ scratch,
                   int n) {
    int i = blockIdx.x * blockDim.x + threadIdx.x;
    if (i >= n) return;
    int lin = cell_lin(pts[3 * i], pts[3 * i + 1], pts[3 * i + 2], bidx[i]);
    atomicMax(&scratch[lin], __float_as_uint(val[i]) + 1u);
}

__global__ void __launch_bounds__(256)
occ_finalize_kernel(const f32x4* __restrict__ grid,
                    f32x4* __restrict__ out_val,
                    f32x4* out_occ /* aliases scratch */,
                    long long nquads) {
    long long i = (long long)blockIdx.x * blockDim.x + threadIdx.x;
    if (i >= nquads) return;
    f32x4 g = __builtin_nontemporal_load(&grid[i]);
    u32x4 s = *reinterpret_cast<const u32x4*>(&out_occ[i]);
    f32x4 r;
    r.x = s.x ? fmaxf(g.x * EMA, __uint_as_float(s.x - 1u)) : g.x;
    r.y = s.y ? fmaxf(g.y * EMA, __uint_as_float(s.y - 1u)) : g.y;
    r.z = s.z ? fmaxf(g.z * EMA, __uint_as_float(s.z - 1u)) : g.z;
    r.w = s.w ? fmaxf(g.w * EMA, __uint_as_float(s.w - 1u)) : g.w;
    f32x4 o;
    o.x = (r.x > THRE) ? 1.0f : 0.0f;
    o.y = (r.y > THRE) ? 1.0f : 0.0f;
    o.z = (r.z > THRE) ? 1.0f : 0.0f;
    o.w = (r.w > THRE) ? 1.0f : 0.0f;
    __builtin_nontemporal_store(r, &out_val[i]);
    __builtin_nontemporal_store(o, &out_occ[i]);
}

extern "C" void kernel_launch(void* const* d_in, const int* in_sizes, int n_in,
                              void* d_out, int out_size, void* d_ws, size_t ws_size,
                              hipStream_t stream) {
    const float* grid = (const float*)d_in[0];   // (B,R,R,R) fp32
    const float* pts  = (const float*)d_in[1];   // (N,3) fp32
    const int*   bidx = (const int*)d_in[2];     // (N,) int32
    const float* val  = (const float*)d_in[3];   // (N,) fp32

    float* out_val = (float*)d_out;              // first G floats: new grid
    float* out_occ = out_val + GCELLS;           // second G floats: occ mask

    int n = in_sizes[1] / 3;                     // N points

    // ws layout: binned pairs | overflow pairs | bucket cursors | ov cursor
    size_t off_binned = 0;
    size_t off_ovbuf  = off_binned + (size_t)NB * CAP * sizeof(uint2); // 65,536,000
    size_t off_gcur   = off_ovbuf + (size_t)OVCAP * sizeof(uint2);     // +524,288
    size_t off_ovcur  = off_gcur + (size_t)NB * sizeof(unsigned int);  // +8,000
    size_t ws_need    = off_ovcur + sizeof(unsigned int);

    if (ws_size >= ws_need) {
        uint2*        binned  = (uint2*)((char*)d_ws + off_binned);
        uint2*        ovbuf   = (uint2*)((char*)d_ws + off_ovbuf);
        unsigned int* gcursor = (unsigned int*)((char*)d_ws + off_gcur);
        unsigned int* ovcur   = (unsigned int*)((char*)d_ws + off_ovcur);

        occ_cursor_zero_kernel<<<1, 256, 0, stream>>>(gcursor, ovcur);
        occ_bin_kernel<<<256, 256, 0, stream>>>(
            pts, bidx, val, binned, gcursor, ovcur, ovbuf, n);
        occ_replay_finalize_kernel<<<NB, 256, 0, stream>>>(
            binned, gcursor, ovcur, ovbuf,
            (const f32x4*)grid, (f32x4*)out_val, (f32x4*)out_occ);
    } else {
        // Fallback: round-1 structure (best measured pre-binning: 547 us)
        long long quads = GCELLS / 4;
        int cell_blocks = (int)((quads + 255) / 256);
        occ_zero_kernel<<<cell_blocks, 256, 0, stream>>>((u32x4*)out_occ, quads);
        int blocks_pts = (n + 255) / 256;
        occ_scatter_kernel<<<blocks_pts, 256, 0, stream>>>(
            pts, bidx, val, (unsigned int*)out_occ, n);
        occ_finalize_kernel<<<cell_blocks, 256, 0, stream>>>(
            (const f32x4*)grid, (f32x4*)out_val, (f32x4*)out_occ, quads);
    }
}